// Round 8
// baseline (542.443 us; speedup 1.0000x reference)
//
#include <hip/hip_runtime.h>
#include <hip/hip_bf16.h>
#include <hip/hip_cooperative_groups.h>
#include <math.h>

namespace cg = cooperative_groups;

typedef __bf16 bf16x8 __attribute__((ext_vector_type(8)));
typedef __bf16 bf16x4 __attribute__((ext_vector_type(4)));
typedef float  f32x4  __attribute__((ext_vector_type(4)));

struct Ctx {
  const float *img, *qst;
  const float *w0, *bs0, *bb0, *w1, *bs1, *bb1, *w2, *bs2, *bb2, *w3, *bs3, *bb3;
  const float *gw1, *gb1, *g2, *g3, *g4, *gb2, *gb3, *gb4;
  const float *fw1, *fb1, *fw2, *fb2, *cw, *cb;
  float *c0, *c1, *hi, *hj, *hq, *sbuf, *out;
  __bf16 *Wt;
};

// ================= phase device functions (shared by mega + fallback kernels) =================

// conv0: 3->24, 128x128 -> 64x64, 2 pos/thread. 512 works.
__device__ __forceinline__ void ph_conv0(const Ctx& A, int w, int t, float* smem) {
  float* wl = smem;                                  // 648
  for (int i = t; i < 648; i += 256) wl[i] = A.w0[i];
  __syncthreads();
  const int H = 128, W = 128, OH = 64, OW = 64;
  int idx = w * 256 + t;
  int oxh = idx & 31; int tt = idx >> 5; int oy = tt & 63; int n = tt >> 6;
  int ox0 = oxh * 2;
  float acc0[24], acc1[24];
#pragma unroll
  for (int co = 0; co < 24; ++co) { acc0[co] = 0.f; acc1[co] = 0.f; }
  for (int ci = 0; ci < 3; ++ci) {
    const float* xp = A.img + (size_t)(n * 3 + ci) * H * W;
#pragma unroll
    for (int ky = 0; ky < 3; ++ky) {
      int iy = 2 * oy + ky - 1;
      if (iy < 0 || iy >= H) continue;
      const float* row = xp + (size_t)iy * W;
      int ixb = 2 * ox0 - 1;
      float in[7];
#pragma unroll
      for (int u = 0; u < 7; ++u) {
        int ix = ixb + u;
        in[u] = (ix >= 0 && ix < W) ? row[ix] : 0.f;
      }
#pragma unroll
      for (int kx = 0; kx < 3; ++kx) {
        const float* wp = &wl[((ky * 3 + kx) * 3 + ci) * 24];
        float v0 = in[kx], v1 = in[kx + 2];
#pragma unroll
        for (int co = 0; co < 24; ++co) {
          float wv = wp[co];
          acc0[co] += v0 * wv;
          acc1[co] += v1 * wv;
        }
      }
    }
  }
  float* yp = A.c0 + (size_t)n * 24 * OH * OW + (size_t)oy * OW + ox0;
#pragma unroll
  for (int co = 0; co < 24; ++co) {
    float s = A.bs0[co], b = A.bb0[co];
    yp[(size_t)co * OH * OW]     = fmaxf(acc0[co] * s + b, 0.f);
    yp[(size_t)co * OH * OW + 1] = fmaxf(acc1[co] * s + b, 0.f);
  }
}

// role1: works [0,256) conv1 co-split | [256,280) wt_frag | [280,344) hq + sbuf zero
__device__ __forceinline__ void ph_role1(const Ctx& A, int w, int t, char* smraw) {
  float* smem = (float*)smraw;
  if (w < 256) {
    // conv1: 24->24, 64x64 -> 32x32, 12 co/block, 2 pos/thread
    float* wl = smem;                                // 2592
    const int half = w & 1, sb = w >> 1;
    for (int i = t; i < 2592; i += 256) {
      int co = i % 12, rest = i / 12;
      wl[i] = A.w1[rest * 24 + half * 12 + co];
    }
    __syncthreads();
    const int H = 64, W = 64, OH = 32, OW = 32;
    int idx = sb * 256 + t;
    int oxh = idx & 15; int tt = idx >> 4; int oy = tt & 31; int n = tt >> 5;
    int ox0 = oxh * 2;
    float acc0[12], acc1[12];
#pragma unroll
    for (int co = 0; co < 12; ++co) { acc0[co] = 0.f; acc1[co] = 0.f; }
    for (int ci = 0; ci < 24; ++ci) {
      const float* xp = A.c0 + (size_t)(n * 24 + ci) * H * W;
#pragma unroll
      for (int ky = 0; ky < 3; ++ky) {
        int iy = 2 * oy + ky - 1;
        if (iy < 0 || iy >= H) continue;
        const float* row = xp + (size_t)iy * W;
        int ixb = 2 * ox0 - 1;
        float in[7];
#pragma unroll
        for (int u = 0; u < 7; ++u) {
          int ix = ixb + u;
          in[u] = (ix >= 0 && ix < W) ? row[ix] : 0.f;
        }
#pragma unroll
        for (int kx = 0; kx < 3; ++kx) {
          const float* wp = &wl[((ky * 3 + kx) * 24 + ci) * 12];
          float v0 = in[kx], v1 = in[kx + 2];
#pragma unroll
          for (int co = 0; co < 12; ++co) {
            float wv = wp[co];
            acc0[co] += v0 * wv;
            acc1[co] += v1 * wv;
          }
        }
      }
    }
    float* yp = A.c1 + (size_t)n * 24 * OH * OW + (size_t)(half * 12) * OH * OW + (size_t)oy * OW + ox0;
#pragma unroll
    for (int co = 0; co < 12; ++co) {
      int cog = half * 12 + co;
      float s = A.bs1[cog], b = A.bb1[cog];
      yp[(size_t)co * OH * OW]     = fmaxf(acc0[co] * s + b, 0.f);
      yp[(size_t)co * OH * OW + 1] = fmaxf(acc1[co] * s + b, 0.f);
    }
  } else if (w < 280) {
    // wt_frag: g_w2/3/4 (256x256 [k][n]) -> Wt bf16 in MFMA-B-fragment order
    float* tile = smem;                              // [32][257] = 32896 B
    const int lb = w - 256;
    const int l = lb >> 3, ks = lb & 7;
    const float* src = (l == 0) ? A.g2 : (l == 1) ? A.g3 : A.g4;
    for (int kk = 0; kk < 32; ++kk) tile[kk * 257 + t] = src[(ks * 32 + kk) * 256 + t];
    __syncthreads();
    const int q = t & 3, nb = t >> 2;
    __bf16* out = A.Wt + (size_t)(l * 8 + ks) * 8192;
#pragma unroll
    for (int i = 0; i < 4; ++i) {
      int nn = i * 64 + nb;
      bf16x8 v;
#pragma unroll
      for (int j = 0; j < 8; ++j) v[j] = (__bf16)tile[(q * 8 + j) * 257 + nn];
      *(bf16x8*)&out[nn * 32 + q * 8] = v;
    }
  } else {
    // hq = qst @ W1c + g_b1 ; zero sbuf
    float* qs = smem;
    const int n = w - 280;
    A.sbuf[n * 256 + t] = 0.f;
    if (t < 128) qs[t] = A.qst[n * 128 + t];
    __syncthreads();
    float a = A.gb1[t];
    for (int c = 0; c < 128; ++c) a += qs[c] * A.gw1[(52 + c) * 256 + t];
    A.hq[n * 256 + t] = a;
  }
}

// chain2: per-n conv2 (->LDS) + conv3 (LDS) + embed -> hi,hj. 64 works.
__device__ __forceinline__ void ph_chain2(const Ctx& A, int w, int t, float* smem) {
  float* sw = smem;                                  // 5184 (w2, then w3)
  float* s2 = smem + 5184;                           // 6144 [24co][256pos]
  float* s3 = smem + 11328;                          // 1536 [24co][64pos]
  const int n = w;
  for (int i = t; i < 5184; i += 256) sw[i] = A.w2[i];
  __syncthreads();
  {  // conv2: thread t = one 16x16 position, all 24 co; reads c1 global
    int ox = t & 15, oy = t >> 4;
    float acc[24];
#pragma unroll
    for (int co = 0; co < 24; ++co) acc[co] = 0.f;
    for (int ci = 0; ci < 24; ++ci) {
      const float* xp = A.c1 + (size_t)(n * 24 + ci) * 1024;  // 32x32
#pragma unroll
      for (int ky = 0; ky < 3; ++ky) {
        int iy = 2 * oy + ky - 1;
        if (iy < 0 || iy >= 32) continue;
#pragma unroll
        for (int kx = 0; kx < 3; ++kx) {
          int ix = 2 * ox + kx - 1;
          if (ix < 0 || ix >= 32) continue;
          float v = xp[iy * 32 + ix];
          const float* wp = &sw[((ky * 3 + kx) * 24 + ci) * 24];
#pragma unroll
          for (int co = 0; co < 24; ++co) acc[co] += v * wp[co];
        }
      }
    }
#pragma unroll
    for (int co = 0; co < 24; ++co)
      s2[co * 256 + t] = fmaxf(acc[co] * A.bs2[co] + A.bb2[co], 0.f);
  }
  __syncthreads();
  for (int i = t; i < 5184; i += 256) sw[i] = A.w3[i];
  __syncthreads();
  {  // conv3: pos = t&63 (8x8), cog = t>>6 covering 6 channels
    const int pos = t & 63, cog = t >> 6;
    const int oy = pos >> 3, ox = pos & 7;
    float acc[6];
#pragma unroll
    for (int u = 0; u < 6; ++u) acc[u] = 0.f;
    for (int ci = 0; ci < 24; ++ci) {
      const float* cp = &s2[ci * 256];
#pragma unroll
      for (int ky = 0; ky < 3; ++ky) {
        int iy = 2 * oy + ky - 1;
        if (iy < 0 || iy >= 16) continue;
#pragma unroll
        for (int kx = 0; kx < 3; ++kx) {
          int ix = 2 * ox + kx - 1;
          if (ix < 0 || ix >= 16) continue;
          float v = cp[iy * 16 + ix];
          const float* wp = &sw[((ky * 3 + kx) * 24 + ci) * 24 + cog * 6];
#pragma unroll
          for (int u = 0; u < 6; ++u) acc[u] += v * wp[u];
        }
      }
    }
#pragma unroll
    for (int u = 0; u < 6; ++u) {
      int co = cog * 6 + u;
      s3[co * 64 + pos] = fmaxf(acc[u] * A.bs3[co] + A.bb3[co], 0.f);
    }
  }
  // embed: thread t = output feature column
  float wa[26], wb[26];
#pragma unroll
  for (int c = 0; c < 26; ++c) {
    wa[c] = A.gw1[c * 256 + t];
    wb[c] = A.gw1[(26 + c) * 256 + t];
  }
  __syncthreads();
  for (int p = 0; p < 64; ++p) {
    float a = 0.f, b = 0.f;
#pragma unroll
    for (int c = 0; c < 24; ++c) {
      float v = s3[c * 64 + p];
      a += v * wa[c];
      b += v * wb[c];
    }
    float cx = -1.f + (2.f / 7.f) * (float)(p & 7);
    float cy = -1.f + (2.f / 7.f) * (float)(p >> 3);
    a += cx * wa[24] + cy * wa[25];
    b += cx * wb[24] + cy * wb[25];
    A.hi[(size_t)(n * 64 + p) * 256 + t] = a;
    A.hj[(size_t)(n * 64 + p) * 256 + t] = b;
  }
}

// g_fused: M=128 rows x 256 feat per work; Hs = [128][256] bf16 (65536 B exactly)
// with per-row rotation swizzle col' = (col + (row&7)*16) & 255 (conflict mitigation).
__device__ __forceinline__ void ph_gfused(const Ctx& A, int blk, int tid, char* smraw) {
  __bf16* Hs = (__bf16*)smraw;
  const int n = blk >> 5, ib = blk & 31;
  const int wave = tid >> 6, lane = tid & 63;
  const int q = lane >> 4, lr = lane & 15;
  const int c0 = (tid & 63) * 4;

  float4 hq4 = *(const float4*)(A.hq + (size_t)n * 256 + c0);
  float4 h0 = *(const float4*)(A.hi + (size_t)(n * 64 + ib * 2)     * 256 + c0);
  float4 h1 = *(const float4*)(A.hi + (size_t)(n * 64 + ib * 2 + 1) * 256 + c0);
  h0.x += hq4.x; h0.y += hq4.y; h0.z += hq4.z; h0.w += hq4.w;
  h1.x += hq4.x; h1.y += hq4.y; h1.z += hq4.z; h1.w += hq4.w;

  const float* hjb = A.hj + (size_t)n * 64 * 256;
#pragma unroll
  for (int it = 0; it < 16; ++it) {
    int j = it * 4 + wave;
    float4 v = *(const float4*)(hjb + j * 256 + c0);
    int rc = (c0 + ((j & 7) << 4)) & 255;
    bf16x4 o;
    o[0] = (__bf16)fmaxf(v.x + h0.x, 0.f);
    o[1] = (__bf16)fmaxf(v.y + h0.y, 0.f);
    o[2] = (__bf16)fmaxf(v.z + h0.z, 0.f);
    o[3] = (__bf16)fmaxf(v.w + h0.w, 0.f);
    *(bf16x4*)&Hs[j * 256 + rc] = o;
    bf16x4 o2;
    o2[0] = (__bf16)fmaxf(v.x + h1.x, 0.f);
    o2[1] = (__bf16)fmaxf(v.y + h1.y, 0.f);
    o2[2] = (__bf16)fmaxf(v.z + h1.z, 0.f);
    o2[3] = (__bf16)fmaxf(v.w + h1.w, 0.f);
    *(bf16x4*)&Hs[(64 + j) * 256 + rc] = o2;
  }
  __syncthreads();

  const int colloc = wave * 64 + lr;
  const __bf16* Bp = A.Wt + (size_t)wave * 2048 + lr * 32 + q * 8;
  const int arot = (lr & 7) << 4;

  for (int l = 0; l < 3; ++l) {
    const __bf16* Bl = Bp + (size_t)l * 65536;
    const float* bl = (l == 0) ? A.gb2 : (l == 1) ? A.gb3 : A.gb4;

    f32x4 acc[8][4];
#pragma unroll
    for (int r = 0; r < 8; ++r)
#pragma unroll
      for (int c = 0; c < 4; ++c) acc[r][c] = (f32x4){0.f, 0.f, 0.f, 0.f};

    for (int ks = 0; ks < 8; ++ks) {
      int astart = (ks * 32 + q * 8 + arot) & 255;
      bf16x8 b[4];
#pragma unroll
      for (int c = 0; c < 4; ++c)
        b[c] = *(const bf16x8*)&Bl[ks * 8192 + c * 512];
      bf16x8 a[8];
#pragma unroll
      for (int r = 0; r < 8; ++r)
        a[r] = *(const bf16x8*)&Hs[(r * 16 + lr) * 256 + astart];
#pragma unroll
      for (int r = 0; r < 8; ++r)
#pragma unroll
        for (int c = 0; c < 4; ++c)
          acc[r][c] = __builtin_amdgcn_mfma_f32_16x16x32_bf16(a[r], b[c], acc[r][c], 0, 0, 0);
    }

    float bias[4];
#pragma unroll
    for (int c = 0; c < 4; ++c) bias[c] = bl[colloc + c * 16];

    if (l < 2) {
      __syncthreads();
#pragma unroll
      for (int r = 0; r < 8; ++r)
#pragma unroll
        for (int c = 0; c < 4; ++c)
#pragma unroll
          for (int reg = 0; reg < 4; ++reg) {
            int row = r * 16 + q * 4 + reg;        // C/D: row = quad*4 + reg
            int wc = (colloc + c * 16 + ((row & 7) << 4)) & 255;
            Hs[row * 256 + wc] = (__bf16)fmaxf(acc[r][c][reg] + bias[c], 0.f);
          }
      __syncthreads();
    } else {
#pragma unroll
      for (int c = 0; c < 4; ++c) {
        float cs = 0.f;
#pragma unroll
        for (int r = 0; r < 8; ++r)
#pragma unroll
          for (int reg = 0; reg < 4; ++reg)
            cs += fmaxf(acc[r][c][reg] + bias[c], 0.f);
        cs += __shfl_xor(cs, 16);
        cs += __shfl_xor(cs, 32);
        if (q == 0) atomicAdd(&A.sbuf[n * 256 + colloc + c * 16], cs);
      }
    }
  }
}

// f_net + classifier + log_softmax. 64 works.
__device__ __forceinline__ void ph_fnet(const Ctx& A, int w, int t, float* smem) {
  float* buf  = smem;
  float* buf2 = smem + 256;
  float* zs   = smem + 512;
  const int n = w;
  buf[t] = A.sbuf[n * 256 + t];
  __syncthreads();
  float a = A.fb1[t];
  for (int c = 0; c < 256; ++c) a += buf[c] * A.fw1[c * 256 + t];
  a = fmaxf(a, 0.f);
  buf2[t] = a;
  __syncthreads();
  float y = A.fb2[t];
  for (int c = 0; c < 256; ++c) y += buf2[c] * A.fw2[c * 256 + t];
  y = fmaxf(y, 0.f);
  __syncthreads();
  buf[t] = y;
  __syncthreads();
  float z = 0.f;
  if (t < 32) {
    z = A.cb[t];
    for (int c = 0; c < 256; ++c) z += buf[c] * A.cw[c * 32 + t];
    zs[t] = z;
  }
  __syncthreads();
  if (t < 32) {
    float m = -1e30f;
    for (int c = 0; c < 32; ++c) m = fmaxf(m, zs[c]);
    float se = 0.f;
    for (int c = 0; c < 32; ++c) se += expf(zs[c] - m);
    A.out[n * 32 + t] = z - m - logf(se);
  }
}

// ================= cooperative mega-kernel (grid-size agnostic) =================
__global__ __launch_bounds__(256, 2) void mega(Ctx A) {
  cg::grid_group grid = cg::this_grid();
  __shared__ __align__(16) char sm[65536];
  const int t = threadIdx.x;
  const int G = gridDim.x;
  for (int w = blockIdx.x; w < 512; w += G)  { __syncthreads(); ph_conv0(A, w, t, (float*)sm); }
  grid.sync();
  for (int w = blockIdx.x; w < 344; w += G)  { __syncthreads(); ph_role1(A, w, t, sm); }
  grid.sync();
  for (int w = blockIdx.x; w < 64; w += G)   { __syncthreads(); ph_chain2(A, w, t, (float*)sm); }
  grid.sync();
  for (int w = blockIdx.x; w < 2048; w += G) { __syncthreads(); ph_gfused(A, w, t, sm); }
  grid.sync();
  for (int w = blockIdx.x; w < 64; w += G)   { __syncthreads(); ph_fnet(A, w, t, (float*)sm); }
}

// ================= stream-ordered fallback kernels =================
__global__ __launch_bounds__(256) void k_conv0(Ctx A) {
  __shared__ float sm[648];
  ph_conv0(A, blockIdx.x, threadIdx.x, sm);
}
__global__ __launch_bounds__(256) void k_role1(Ctx A) {
  __shared__ __align__(16) char sm[32896];
  ph_role1(A, blockIdx.x, threadIdx.x, sm);
}
__global__ __launch_bounds__(256) void k_chain2(Ctx A) {
  __shared__ float sm[12864];
  ph_chain2(A, blockIdx.x, threadIdx.x, sm);
}
__global__ __launch_bounds__(256, 2) void k_gfused(Ctx A) {
  __shared__ __align__(16) char sm[65536];
  ph_gfused(A, blockIdx.x, threadIdx.x, sm);
}
__global__ __launch_bounds__(256) void k_fnet(Ctx A) {
  __shared__ float sm[544];
  ph_fnet(A, blockIdx.x, threadIdx.x, sm);
}

extern "C" void kernel_launch(void* const* d_in, const int* in_sizes, int n_in,
                              void* d_out, int out_size, void* d_ws, size_t ws_size,
                              hipStream_t stream) {
  char* ws = (char*)d_ws;
  float* c0 = (float*)(ws + 0);                    // 25,165,824 B (dead after conv1 reads it)
  float* c1 = (float*)(ws + 25165824);             //  6,291,456 B -> 31,457,280
  __bf16* Wt  = (__bf16*)(ws + 31457280);          //   393,216 B -> 31,850,496 (outside c0)
  float*  hqb = (float*)(ws + 31850496);           //    65,536 B -> 31,916,032
  float*  sbuf = (float*)(ws + 31916032);          //    65,536 B -> 31,981,568
  float*  hi  = (float*)(ws + 0);                  // 4,194,304 B (dead-c0 region, written in chain2)
  float*  hj  = (float*)(ws + 4194304);            // 4,194,304 B

  Ctx A;
  A.img = (const float*)d_in[0];  A.qst = (const float*)d_in[1];
  A.w0  = (const float*)d_in[2];  A.bs0 = (const float*)d_in[6];  A.bb0 = (const float*)d_in[7];
  A.w1  = (const float*)d_in[3];  A.bs1 = (const float*)d_in[8];  A.bb1 = (const float*)d_in[9];
  A.w2  = (const float*)d_in[4];  A.bs2 = (const float*)d_in[10]; A.bb2 = (const float*)d_in[11];
  A.w3  = (const float*)d_in[5];  A.bs3 = (const float*)d_in[12]; A.bb3 = (const float*)d_in[13];
  A.gw1 = (const float*)d_in[14]; A.gb1 = (const float*)d_in[15];
  A.g2  = (const float*)d_in[16]; A.gb2 = (const float*)d_in[17];
  A.g3  = (const float*)d_in[18]; A.gb3 = (const float*)d_in[19];
  A.g4  = (const float*)d_in[20]; A.gb4 = (const float*)d_in[21];
  A.fw1 = (const float*)d_in[22]; A.fb1 = (const float*)d_in[23];
  A.fw2 = (const float*)d_in[24]; A.fb2 = (const float*)d_in[25];
  A.cw  = (const float*)d_in[26]; A.cb  = (const float*)d_in[27];
  A.c0 = c0; A.c1 = c1; A.hi = hi; A.hj = hj; A.hq = hqb; A.sbuf = sbuf;
  A.Wt = Wt; A.out = (float*)d_out;

  // Capture-safe queries (no stream ops) to decide the launch path deterministically.
  int dev = 0;
  hipGetDevice(&dev);
  int coopSupported = 0;
  hipDeviceGetAttribute(&coopSupported, hipDeviceAttributeCooperativeLaunch, dev);
  int numCU = 0;
  hipDeviceGetAttribute(&numCU, hipDeviceAttributeMultiprocessorCount, dev);
  int nb = 0;
  hipError_t qe = hipOccupancyMaxActiveBlocksPerMultiprocessor(&nb, (const void*)mega, 256, 0);
  long long maxg = (qe == hipSuccess && numCU > 0) ? (long long)nb * numCU : 0;

  if (coopSupported && maxg >= 64) {
    int grid = (int)(maxg < 512 ? maxg : 512);
    void* params[] = { &A };
    hipLaunchCooperativeKernel((const void*)mega, dim3(grid), dim3(256), params, 0, stream);
  } else {
    k_conv0<<<512, 256, 0, stream>>>(A);
    k_role1<<<344, 256, 0, stream>>>(A);
    k_chain2<<<64, 256, 0, stream>>>(A);
    k_gfused<<<2048, 256, 0, stream>>>(A);
    k_fnet<<<64, 256, 0, stream>>>(A);
  }
}

// Round 9
// 361.542 us; speedup vs baseline: 1.5004x; 1.5004x over previous
//
#include <hip/hip_runtime.h>
#include <hip/hip_bf16.h>
#include <math.h>

typedef __bf16 bf16x8 __attribute__((ext_vector_type(8)));
typedef __bf16 bf16x4 __attribute__((ext_vector_type(4)));
typedef float  f32x4  __attribute__((ext_vector_type(4)));

#define LH 264   // Hs row stride in bf16 elems (528 B)

// ---------------- K1: conv0 (512 blk) | wt_frag (24 blk) | hq + sbuf zero (64 blk) -----------
__global__ __launch_bounds__(256) void k1(const float* __restrict__ img, const float* __restrict__ w0,
    const float* __restrict__ bs0, const float* __restrict__ bb0,
    const float* __restrict__ g2, const float* __restrict__ g3, const float* __restrict__ g4,
    const float* __restrict__ gw1, const float* __restrict__ gb1, const float* __restrict__ qst,
    float* __restrict__ c0, __bf16* __restrict__ Wt, float* __restrict__ hq,
    float* __restrict__ sbuf) {
  __shared__ __align__(16) float smem[8224];   // wt tile [32][257] is the max user
  const int blk = blockIdx.x, t = threadIdx.x;

  if (blk < 512) {
    // ---- conv0: 3->24, 128x128 -> 64x64, 2 pos/thread ----
    float* wl = smem;                          // 648
    for (int i = t; i < 648; i += 256) wl[i] = w0[i];
    __syncthreads();
    const int H = 128, W = 128, OH = 64, OW = 64;
    int idx = blk * 256 + t;
    int oxh = idx & 31; int tt = idx >> 5; int oy = tt & 63; int n = tt >> 6;
    int ox0 = oxh * 2;
    float acc0[24], acc1[24];
#pragma unroll
    for (int co = 0; co < 24; ++co) { acc0[co] = 0.f; acc1[co] = 0.f; }
    for (int ci = 0; ci < 3; ++ci) {
      const float* xp = img + (size_t)(n * 3 + ci) * H * W;
#pragma unroll
      for (int ky = 0; ky < 3; ++ky) {
        int iy = 2 * oy + ky - 1;
        if (iy < 0 || iy >= H) continue;
        const float* row = xp + (size_t)iy * W;
        int ixb = 2 * ox0 - 1;
        float in[7];
#pragma unroll
        for (int u = 0; u < 7; ++u) {
          int ix = ixb + u;
          in[u] = (ix >= 0 && ix < W) ? row[ix] : 0.f;
        }
#pragma unroll
        for (int kx = 0; kx < 3; ++kx) {
          const float* wp = &wl[((ky * 3 + kx) * 3 + ci) * 24];
          float v0 = in[kx], v1 = in[kx + 2];
#pragma unroll
          for (int co = 0; co < 24; ++co) {
            float wv = wp[co];
            acc0[co] += v0 * wv;
            acc1[co] += v1 * wv;
          }
        }
      }
    }
    float* yp = c0 + (size_t)n * 24 * OH * OW + (size_t)oy * OW + ox0;
#pragma unroll
    for (int co = 0; co < 24; ++co) {
      float s = bs0[co], b = bb0[co];
      yp[(size_t)co * OH * OW]     = fmaxf(acc0[co] * s + b, 0.f);
      yp[(size_t)co * OH * OW + 1] = fmaxf(acc1[co] * s + b, 0.f);
    }
  } else if (blk < 536) {
    // ---- wt_frag: g_w2/3/4 (256x256 [k][n]) -> Wt bf16 MFMA-B-fragment order ----
    float* tile = smem;                        // [32][257]
    const int lb = blk - 512;
    const int l = lb >> 3, ks = lb & 7;
    const float* src = (l == 0) ? g2 : (l == 1) ? g3 : g4;
    for (int kk = 0; kk < 32; ++kk) tile[kk * 257 + t] = src[(ks * 32 + kk) * 256 + t];
    __syncthreads();
    const int q = t & 3, nb = t >> 2;
    __bf16* out = Wt + (size_t)(l * 8 + ks) * 8192;
#pragma unroll
    for (int i = 0; i < 4; ++i) {
      int nn = i * 64 + nb;
      bf16x8 v;
#pragma unroll
      for (int j = 0; j < 8; ++j) v[j] = (__bf16)tile[(q * 8 + j) * 257 + nn];
      *(bf16x8*)&out[nn * 32 + q * 8] = v;
    }
  } else {
    // ---- hq = qst @ W1c + g_b1 ; zero sbuf ----
    float* qs = smem;
    const int n = blk - 536;
    sbuf[n * 256 + t] = 0.f;
    if (t < 128) qs[t] = qst[n * 128 + t];
    __syncthreads();
    float a = gb1[t];
    for (int c = 0; c < 128; ++c) a += qs[c] * gw1[(52 + c) * 256 + t];
    hq[n * 256 + t] = a;
  }
}

// ---------------- K2: conv1 (24->24, 64x64 -> 32x32), co-split 12/block, 2 pos/thread --------
__global__ __launch_bounds__(256) void conv1_k(const float* __restrict__ x, const float* __restrict__ w,
                                               const float* __restrict__ sc, const float* __restrict__ bi,
                                               float* __restrict__ y) {
  const int H = 64, W = 64, OH = 32, OW = 32;
  __shared__ float wl[2592];
  const int half = blockIdx.x & 1, sb = blockIdx.x >> 1;
  for (int i = threadIdx.x; i < 2592; i += 256) {
    int co = i % 12, rest = i / 12;
    wl[i] = w[rest * 24 + half * 12 + co];
  }
  __syncthreads();

  int idx = sb * 256 + threadIdx.x;
  int oxh = idx & 15; int tt = idx >> 4; int oy = tt & 31; int n = tt >> 5;
  int ox0 = oxh * 2;

  float acc0[12], acc1[12];
#pragma unroll
  for (int co = 0; co < 12; ++co) { acc0[co] = 0.f; acc1[co] = 0.f; }

  for (int ci = 0; ci < 24; ++ci) {
    const float* xp = x + (size_t)(n * 24 + ci) * H * W;
#pragma unroll
    for (int ky = 0; ky < 3; ++ky) {
      int iy = 2 * oy + ky - 1;
      if (iy < 0 || iy >= H) continue;
      const float* row = xp + (size_t)iy * W;
      int ixb = 2 * ox0 - 1;
      float in[7];
#pragma unroll
      for (int u = 0; u < 7; ++u) {
        int ix = ixb + u;
        in[u] = (ix >= 0 && ix < W) ? row[ix] : 0.f;
      }
#pragma unroll
      for (int kx = 0; kx < 3; ++kx) {
        const float* wp = &wl[((ky * 3 + kx) * 24 + ci) * 12];
        float v0 = in[kx], v1 = in[kx + 2];
#pragma unroll
        for (int co = 0; co < 12; ++co) {
          float wv = wp[co];
          acc0[co] += v0 * wv;
          acc1[co] += v1 * wv;
        }
      }
    }
  }
  float* yp = y + (size_t)n * 24 * OH * OW + (size_t)(half * 12) * OH * OW + (size_t)oy * OW + ox0;
#pragma unroll
  for (int co = 0; co < 12; ++co) {
    int cog = half * 12 + co;
    float s = sc[cog], b = bi[cog];
    yp[(size_t)co * OH * OW]     = fmaxf(acc0[co] * s + b, 0.f);
    yp[(size_t)co * OH * OW + 1] = fmaxf(acc1[co] * s + b, 0.f);
  }
}

// ---------------- K3: per-n conv2 (->LDS) + conv3 (LDS) + embed -> hi,hj ----------------
__global__ __launch_bounds__(256) void chain2_k(const float* __restrict__ c1,
    const float* __restrict__ w2, const float* __restrict__ bs2, const float* __restrict__ bb2,
    const float* __restrict__ w3, const float* __restrict__ bs3, const float* __restrict__ bb3,
    const float* __restrict__ gw1, float* __restrict__ hi, float* __restrict__ hj) {
  __shared__ float sw[5184];
  __shared__ float s2[6144];     // [24co][256pos]
  __shared__ float s3[1536];     // [24co][64pos]
  const int n = blockIdx.x, t = threadIdx.x;
  for (int i = t; i < 5184; i += 256) sw[i] = w2[i];
  __syncthreads();
  {  // conv2: thread t = one 16x16 position, all 24 co; reads c1 global
    int ox = t & 15, oy = t >> 4;
    float acc[24];
#pragma unroll
    for (int co = 0; co < 24; ++co) acc[co] = 0.f;
    for (int ci = 0; ci < 24; ++ci) {
      const float* xp = c1 + (size_t)(n * 24 + ci) * 1024;  // 32x32
#pragma unroll
      for (int ky = 0; ky < 3; ++ky) {
        int iy = 2 * oy + ky - 1;
        if (iy < 0 || iy >= 32) continue;
#pragma unroll
        for (int kx = 0; kx < 3; ++kx) {
          int ix = 2 * ox + kx - 1;
          if (ix < 0 || ix >= 32) continue;
          float v = xp[iy * 32 + ix];
          const float* wp = &sw[((ky * 3 + kx) * 24 + ci) * 24];
#pragma unroll
          for (int co = 0; co < 24; ++co) acc[co] += v * wp[co];
        }
      }
    }
#pragma unroll
    for (int co = 0; co < 24; ++co)
      s2[co * 256 + t] = fmaxf(acc[co] * bs2[co] + bb2[co], 0.f);
  }
  __syncthreads();
  for (int i = t; i < 5184; i += 256) sw[i] = w3[i];
  __syncthreads();
  {  // conv3: pos = t&63 (8x8), cog = t>>6 covering 6 channels
    const int pos = t & 63, cog = t >> 6;
    const int oy = pos >> 3, ox = pos & 7;
    float acc[6];
#pragma unroll
    for (int u = 0; u < 6; ++u) acc[u] = 0.f;
    for (int ci = 0; ci < 24; ++ci) {
      const float* cp = &s2[ci * 256];
#pragma unroll
      for (int ky = 0; ky < 3; ++ky) {
        int iy = 2 * oy + ky - 1;
        if (iy < 0 || iy >= 16) continue;
#pragma unroll
        for (int kx = 0; kx < 3; ++kx) {
          int ix = 2 * ox + kx - 1;
          if (ix < 0 || ix >= 16) continue;
          float v = cp[iy * 16 + ix];
          const float* wp = &sw[((ky * 3 + kx) * 24 + ci) * 24 + cog * 6];
#pragma unroll
          for (int u = 0; u < 6; ++u) acc[u] += v * wp[u];
        }
      }
    }
#pragma unroll
    for (int u = 0; u < 6; ++u) {
      int co = cog * 6 + u;
      s3[co * 64 + pos] = fmaxf(acc[u] * bs3[co] + bb3[co], 0.f);
    }
  }
  // embed: thread t = output feature column
  float wa[26], wb[26];
#pragma unroll
  for (int c = 0; c < 26; ++c) {
    wa[c] = gw1[c * 256 + t];
    wb[c] = gw1[(26 + c) * 256 + t];
  }
  __syncthreads();
  for (int p = 0; p < 64; ++p) {
    float a = 0.f, b = 0.f;
#pragma unroll
    for (int c = 0; c < 24; ++c) {
      float v = s3[c * 64 + p];
      a += v * wa[c];
      b += v * wb[c];
    }
    float cx = -1.f + (2.f / 7.f) * (float)(p & 7);
    float cy = -1.f + (2.f / 7.f) * (float)(p >> 3);
    a += cx * wa[24] + cy * wa[25];
    b += cx * wb[24] + cy * wb[25];
    hi[(size_t)(n * 64 + p) * 256 + t] = a;
    hj[(size_t)(n * 64 + p) * 256 + t] = b;
  }
}

// ---------------- K4: fused relation network; wave = 4 row-tiles x 8 col-tiles ----------------
// r4 x c8 halves LDS A-fragment reads vs r8 x c4 (B comes from L2, off the LDS pipe).
__global__ __launch_bounds__(256, 2)
void g_fused(const float* __restrict__ hi, const float* __restrict__ hj,
             const float* __restrict__ hq, const __bf16* __restrict__ Wt,
             const float* __restrict__ b2, const float* __restrict__ b3,
             const float* __restrict__ b4, float* __restrict__ s_out) {
  const int blk = blockIdx.x;          // n*32 + ib ; i = 2*ib, 2*ib+1
  const int n = blk >> 5, ib = blk & 31;
  const int tid = threadIdx.x;
  const int wave = tid >> 6, lane = tid & 63;
  const int q = lane >> 4, lr = lane & 15;

  __shared__ __align__(16) __bf16 Hs[128 * LH];

  const int c0 = (tid & 63) * 4;
  float4 hq4 = *(const float4*)(hq + (size_t)n * 256 + c0);
  float4 h0 = *(const float4*)(hi + (size_t)(n * 64 + ib * 2)     * 256 + c0);
  float4 h1 = *(const float4*)(hi + (size_t)(n * 64 + ib * 2 + 1) * 256 + c0);
  h0.x += hq4.x; h0.y += hq4.y; h0.z += hq4.z; h0.w += hq4.w;
  h1.x += hq4.x; h1.y += hq4.y; h1.z += hq4.z; h1.w += hq4.w;

  const float* hjb = hj + (size_t)n * 64 * 256;
#pragma unroll
  for (int it = 0; it < 16; ++it) {
    int j = it * 4 + wave;
    float4 v = *(const float4*)(hjb + j * 256 + c0);
    bf16x4 o;
    o[0] = (__bf16)fmaxf(v.x + h0.x, 0.f);
    o[1] = (__bf16)fmaxf(v.y + h0.y, 0.f);
    o[2] = (__bf16)fmaxf(v.z + h0.z, 0.f);
    o[3] = (__bf16)fmaxf(v.w + h0.w, 0.f);
    *(bf16x4*)&Hs[j * LH + c0] = o;
    bf16x4 o2;
    o2[0] = (__bf16)fmaxf(v.x + h1.x, 0.f);
    o2[1] = (__bf16)fmaxf(v.y + h1.y, 0.f);
    o2[2] = (__bf16)fmaxf(v.z + h1.z, 0.f);
    o2[3] = (__bf16)fmaxf(v.w + h1.w, 0.f);
    *(bf16x4*)&Hs[(64 + j) * LH + c0] = o2;
  }
  __syncthreads();

  const int rbase = (wave >> 1) * 64;          // rows rbase + r*16, r=0..3
  const int cbase = (wave & 1) * 128;          // cols cbase + c*16 + lr, c=0..7
  // fragment-ordered weights: elem(ks, n, q, j) at (ks*256 + n)*32 + q*8 + j
  const __bf16* Bp = Wt + (size_t)cbase * 32 + lr * 32 + q * 8;

  for (int l = 0; l < 3; ++l) {
    const __bf16* Bl = Bp + (size_t)l * 65536;
    const float* bl = (l == 0) ? b2 : (l == 1) ? b3 : b4;

    f32x4 acc[4][8];
#pragma unroll
    for (int r = 0; r < 4; ++r)
#pragma unroll
      for (int c = 0; c < 8; ++c) acc[r][c] = (f32x4){0.f, 0.f, 0.f, 0.f};

    for (int ks = 0; ks < 8; ++ks) {
      bf16x8 b[8];
#pragma unroll
      for (int c = 0; c < 8; ++c)
        b[c] = *(const bf16x8*)&Bl[ks * 8192 + c * 512];
      bf16x8 a[4];
#pragma unroll
      for (int r = 0; r < 4; ++r)
        a[r] = *(const bf16x8*)&Hs[(rbase + r * 16 + lr) * LH + ks * 32 + q * 8];
#pragma unroll
      for (int r = 0; r < 4; ++r)
#pragma unroll
        for (int c = 0; c < 8; ++c)
          acc[r][c] = __builtin_amdgcn_mfma_f32_16x16x32_bf16(a[r], b[c], acc[r][c], 0, 0, 0);
    }

    float bias[8];
#pragma unroll
    for (int c = 0; c < 8; ++c) bias[c] = bl[cbase + c * 16 + lr];

    if (l < 2) {
      __syncthreads();
#pragma unroll
      for (int r = 0; r < 4; ++r)
#pragma unroll
        for (int c = 0; c < 8; ++c)
#pragma unroll
          for (int reg = 0; reg < 4; ++reg) {
            int row = rbase + r * 16 + q * 4 + reg;   // C/D: row = quad*4 + reg
            Hs[row * LH + cbase + c * 16 + lr] = (__bf16)fmaxf(acc[r][c][reg] + bias[c], 0.f);
          }
      __syncthreads();
    } else {
      // final layer: relu + column-sum over this wave's 64 rows, then atomicAdd
#pragma unroll
      for (int c = 0; c < 8; ++c) {
        float cs = 0.f;
#pragma unroll
        for (int r = 0; r < 4; ++r)
#pragma unroll
          for (int reg = 0; reg < 4; ++reg)
            cs += fmaxf(acc[r][c][reg] + bias[c], 0.f);
        cs += __shfl_xor(cs, 16);
        cs += __shfl_xor(cs, 32);
        if (q == 0) atomicAdd(&s_out[n * 256 + cbase + c * 16 + lr], cs);
      }
    }
  }
}

// ---------------- K5: f-network + classifier + log_softmax ----------------
__global__ void f_net(const float* __restrict__ s, const float* __restrict__ fw1,
                      const float* __restrict__ fb1, const float* __restrict__ fw2,
                      const float* __restrict__ fb2, const float* __restrict__ cw,
                      const float* __restrict__ cb, float* __restrict__ out) {
  int n = blockIdx.x, t = threadIdx.x;
  __shared__ float buf[256], buf2[256], zs[32];
  buf[t] = s[n * 256 + t];
  __syncthreads();
  float a = fb1[t];
  for (int c = 0; c < 256; ++c) a += buf[c] * fw1[c * 256 + t];
  a = fmaxf(a, 0.f);
  buf2[t] = a;
  __syncthreads();
  float y = fb2[t];
  for (int c = 0; c < 256; ++c) y += buf2[c] * fw2[c * 256 + t];
  y = fmaxf(y, 0.f);
  __syncthreads();
  buf[t] = y;
  __syncthreads();
  float z = 0.f;
  if (t < 32) {
    z = cb[t];
    for (int c = 0; c < 256; ++c) z += buf[c] * cw[c * 32 + t];
    zs[t] = z;
  }
  __syncthreads();
  if (t < 32) {
    float m = -1e30f;
    for (int c = 0; c < 32; ++c) m = fmaxf(m, zs[c]);
    float se = 0.f;
    for (int c = 0; c < 32; ++c) se += expf(zs[c] - m);
    out[n * 32 + t] = z - m - logf(se);
  }
}

extern "C" void kernel_launch(void* const* d_in, const int* in_sizes, int n_in,
                              void* d_out, int out_size, void* d_ws, size_t ws_size,
                              hipStream_t stream) {
  const float* img  = (const float*)d_in[0];
  const float* qst  = (const float*)d_in[1];
  const float* w0   = (const float*)d_in[2];
  const float* w1   = (const float*)d_in[3];
  const float* w2   = (const float*)d_in[4];
  const float* w3   = (const float*)d_in[5];
  const float* bs0  = (const float*)d_in[6];
  const float* bb0  = (const float*)d_in[7];
  const float* bs1  = (const float*)d_in[8];
  const float* bb1  = (const float*)d_in[9];
  const float* bs2  = (const float*)d_in[10];
  const float* bb2  = (const float*)d_in[11];
  const float* bs3  = (const float*)d_in[12];
  const float* bb3  = (const float*)d_in[13];
  const float* gw1  = (const float*)d_in[14];
  const float* gb1  = (const float*)d_in[15];
  const float* gw2  = (const float*)d_in[16];
  const float* gb2  = (const float*)d_in[17];
  const float* gw3  = (const float*)d_in[18];
  const float* gb3  = (const float*)d_in[19];
  const float* gw4  = (const float*)d_in[20];
  const float* gb4  = (const float*)d_in[21];
  const float* fw1  = (const float*)d_in[22];
  const float* fb1  = (const float*)d_in[23];
  const float* fw2  = (const float*)d_in[24];
  const float* fb2  = (const float*)d_in[25];
  const float* cw   = (const float*)d_in[26];
  const float* cb   = (const float*)d_in[27];

  char* ws = (char*)d_ws;
  float* c0 = (float*)(ws + 0);                    // 25,165,824 B (dead after conv1 reads it)
  float* c1 = (float*)(ws + 25165824);             //  6,291,456 B -> 31,457,280
  __bf16* Wt  = (__bf16*)(ws + 31457280);          //   393,216 B -> 31,850,496 (outside c0)
  float*  hqb = (float*)(ws + 31850496);           //    65,536 B -> 31,916,032
  float*  sbuf = (float*)(ws + 31916032);          //    65,536 B -> 31,981,568
  float*  hi  = (float*)(ws + 0);                  // 4,194,304 B (dead-c0, written in K3)
  float*  hj  = (float*)(ws + 4194304);            // 4,194,304 B

  k1<<<600, 256, 0, stream>>>(img, w0, bs0, bb0, gw2, gw3, gw4, gw1, gb1, qst,
                              c0, Wt, hqb, sbuf);
  conv1_k<<<256, 256, 0, stream>>>(c0, w1, bs1, bb1, c1);
  chain2_k<<<64, 256, 0, stream>>>(c1, w2, bs2, bb2, w3, bs3, bb3, gw1, hi, hj);
  g_fused<<<2048, 256, 0, stream>>>(hi, hj, hqb, Wt, gb2, gb3, gb4, sbuf);
  f_net<<<64, 256, 0, stream>>>(sbuf, fw1, fb1, fw2, fb2, cw, cb, (float*)d_out);
}

// Round 10
// 311.463 us; speedup vs baseline: 1.7416x; 1.1608x over previous
//
#include <hip/hip_runtime.h>
#include <hip/hip_bf16.h>
#include <math.h>

typedef __bf16 bf16x8 __attribute__((ext_vector_type(8)));
typedef __bf16 bf16x4 __attribute__((ext_vector_type(4)));
typedef float  f32x4  __attribute__((ext_vector_type(4)));

#define LH 264   // Hs row stride in bf16 elems (528 B)

// ---------------- K1: conv0 (512 blk) | wt_frag (24 blk) | hq + sbuf zero (64 blk) -----------
__global__ __launch_bounds__(256) void k1(const float* __restrict__ img, const float* __restrict__ w0,
    const float* __restrict__ bs0, const float* __restrict__ bb0,
    const float* __restrict__ g2, const float* __restrict__ g3, const float* __restrict__ g4,
    const float* __restrict__ gw1, const float* __restrict__ gb1, const float* __restrict__ qst,
    float* __restrict__ c0, __bf16* __restrict__ Wt, float* __restrict__ hq,
    float* __restrict__ sbuf) {
  __shared__ __align__(16) float smem[8224];   // wt tile [32][257] is the max user
  const int blk = blockIdx.x, t = threadIdx.x;

  if (blk < 512) {
    // ---- conv0: 3->24, 128x128 -> 64x64, 2 pos/thread ----
    float* wl = smem;                          // 648
    for (int i = t; i < 648; i += 256) wl[i] = w0[i];
    __syncthreads();
    const int H = 128, W = 128, OH = 64, OW = 64;
    int idx = blk * 256 + t;
    int oxh = idx & 31; int tt = idx >> 5; int oy = tt & 63; int n = tt >> 6;
    int ox0 = oxh * 2;
    float acc0[24], acc1[24];
#pragma unroll
    for (int co = 0; co < 24; ++co) { acc0[co] = 0.f; acc1[co] = 0.f; }
    for (int ci = 0; ci < 3; ++ci) {
      const float* xp = img + (size_t)(n * 3 + ci) * H * W;
#pragma unroll
      for (int ky = 0; ky < 3; ++ky) {
        int iy = 2 * oy + ky - 1;
        if (iy < 0 || iy >= H) continue;
        const float* row = xp + (size_t)iy * W;
        int ixb = 2 * ox0 - 1;
        float in[7];
#pragma unroll
        for (int u = 0; u < 7; ++u) {
          int ix = ixb + u;
          in[u] = (ix >= 0 && ix < W) ? row[ix] : 0.f;
        }
#pragma unroll
        for (int kx = 0; kx < 3; ++kx) {
          const float* wp = &wl[((ky * 3 + kx) * 3 + ci) * 24];
          float v0 = in[kx], v1 = in[kx + 2];
#pragma unroll
          for (int co = 0; co < 24; ++co) {
            float wv = wp[co];
            acc0[co] += v0 * wv;
            acc1[co] += v1 * wv;
          }
        }
      }
    }
    float* yp = c0 + (size_t)n * 24 * OH * OW + (size_t)oy * OW + ox0;
#pragma unroll
    for (int co = 0; co < 24; ++co) {
      float s = bs0[co], b = bb0[co];
      yp[(size_t)co * OH * OW]     = fmaxf(acc0[co] * s + b, 0.f);
      yp[(size_t)co * OH * OW + 1] = fmaxf(acc1[co] * s + b, 0.f);
    }
  } else if (blk < 536) {
    // ---- wt_frag: g_w2/3/4 (256x256 [k][n]) -> Wt bf16 MFMA-B-fragment order ----
    float* tile = smem;                        // [32][257]
    const int lb = blk - 512;
    const int l = lb >> 3, ks = lb & 7;
    const float* src = (l == 0) ? g2 : (l == 1) ? g3 : g4;
    for (int kk = 0; kk < 32; ++kk) tile[kk * 257 + t] = src[(ks * 32 + kk) * 256 + t];
    __syncthreads();
    const int q = t & 3, nb = t >> 2;
    __bf16* out = Wt + (size_t)(l * 8 + ks) * 8192;
#pragma unroll
    for (int i = 0; i < 4; ++i) {
      int nn = i * 64 + nb;
      bf16x8 v;
#pragma unroll
      for (int j = 0; j < 8; ++j) v[j] = (__bf16)tile[(q * 8 + j) * 257 + nn];
      *(bf16x8*)&out[nn * 32 + q * 8] = v;
    }
  } else {
    // ---- hq = qst @ W1c + g_b1 ; zero sbuf ----
    float* qs = smem;
    const int n = blk - 536;
    sbuf[n * 256 + t] = 0.f;
    if (t < 128) qs[t] = qst[n * 128 + t];
    __syncthreads();
    float a = gb1[t];
    for (int c = 0; c < 128; ++c) a += qs[c] * gw1[(52 + c) * 256 + t];
    hq[n * 256 + t] = a;
  }
}

// ---------------- K2: conv1 (24->24, 64x64 -> 32x32), co-split 12/block, 2 pos/thread --------
__global__ __launch_bounds__(256) void conv1_k(const float* __restrict__ x, const float* __restrict__ w,
                                               const float* __restrict__ sc, const float* __restrict__ bi,
                                               float* __restrict__ y) {
  const int H = 64, W = 64, OH = 32, OW = 32;
  __shared__ float wl[2592];
  const int half = blockIdx.x & 1, sb = blockIdx.x >> 1;
  for (int i = threadIdx.x; i < 2592; i += 256) {
    int co = i % 12, rest = i / 12;
    wl[i] = w[rest * 24 + half * 12 + co];
  }
  __syncthreads();

  int idx = sb * 256 + threadIdx.x;
  int oxh = idx & 15; int tt = idx >> 4; int oy = tt & 31; int n = tt >> 5;
  int ox0 = oxh * 2;

  float acc0[12], acc1[12];
#pragma unroll
  for (int co = 0; co < 12; ++co) { acc0[co] = 0.f; acc1[co] = 0.f; }

  for (int ci = 0; ci < 24; ++ci) {
    const float* xp = x + (size_t)(n * 24 + ci) * H * W;
#pragma unroll
    for (int ky = 0; ky < 3; ++ky) {
      int iy = 2 * oy + ky - 1;
      if (iy < 0 || iy >= H) continue;
      const float* row = xp + (size_t)iy * W;
      int ixb = 2 * ox0 - 1;
      float in[7];
#pragma unroll
      for (int u = 0; u < 7; ++u) {
        int ix = ixb + u;
        in[u] = (ix >= 0 && ix < W) ? row[ix] : 0.f;
      }
#pragma unroll
      for (int kx = 0; kx < 3; ++kx) {
        const float* wp = &wl[((ky * 3 + kx) * 24 + ci) * 12];
        float v0 = in[kx], v1 = in[kx + 2];
#pragma unroll
        for (int co = 0; co < 12; ++co) {
          float wv = wp[co];
          acc0[co] += v0 * wv;
          acc1[co] += v1 * wv;
        }
      }
    }
  }
  float* yp = y + (size_t)n * 24 * OH * OW + (size_t)(half * 12) * OH * OW + (size_t)oy * OW + ox0;
#pragma unroll
  for (int co = 0; co < 12; ++co) {
    int cog = half * 12 + co;
    float s = sc[cog], b = bi[cog];
    yp[(size_t)co * OH * OW]     = fmaxf(acc0[co] * s + b, 0.f);
    yp[(size_t)co * OH * OW + 1] = fmaxf(acc1[co] * s + b, 0.f);
  }
}

// ---------------- K3: per-n conv2 (->LDS) + conv3 (LDS) + embed -> hi,hj ----------------
__global__ __launch_bounds__(256) void chain2_k(const float* __restrict__ c1,
    const float* __restrict__ w2, const float* __restrict__ bs2, const float* __restrict__ bb2,
    const float* __restrict__ w3, const float* __restrict__ bs3, const float* __restrict__ bb3,
    const float* __restrict__ gw1, float* __restrict__ hi, float* __restrict__ hj) {
  __shared__ float sw[5184];
  __shared__ float s2[6144];     // [24co][256pos]
  __shared__ float s3[1536];     // [24co][64pos]
  const int n = blockIdx.x, t = threadIdx.x;
  for (int i = t; i < 5184; i += 256) sw[i] = w2[i];
  __syncthreads();
  {  // conv2: thread t = one 16x16 position, all 24 co; reads c1 global
    int ox = t & 15, oy = t >> 4;
    float acc[24];
#pragma unroll
    for (int co = 0; co < 24; ++co) acc[co] = 0.f;
    for (int ci = 0; ci < 24; ++ci) {
      const float* xp = c1 + (size_t)(n * 24 + ci) * 1024;  // 32x32
#pragma unroll
      for (int ky = 0; ky < 3; ++ky) {
        int iy = 2 * oy + ky - 1;
        if (iy < 0 || iy >= 32) continue;
#pragma unroll
        for (int kx = 0; kx < 3; ++kx) {
          int ix = 2 * ox + kx - 1;
          if (ix < 0 || ix >= 32) continue;
          float v = xp[iy * 32 + ix];
          const float* wp = &sw[((ky * 3 + kx) * 24 + ci) * 24];
#pragma unroll
          for (int co = 0; co < 24; ++co) acc[co] += v * wp[co];
        }
      }
    }
#pragma unroll
    for (int co = 0; co < 24; ++co)
      s2[co * 256 + t] = fmaxf(acc[co] * bs2[co] + bb2[co], 0.f);
  }
  __syncthreads();
  for (int i = t; i < 5184; i += 256) sw[i] = w3[i];
  __syncthreads();
  {  // conv3: pos = t&63 (8x8), cog = t>>6 covering 6 channels
    const int pos = t & 63, cog = t >> 6;
    const int oy = pos >> 3, ox = pos & 7;
    float acc[6];
#pragma unroll
    for (int u = 0; u < 6; ++u) acc[u] = 0.f;
    for (int ci = 0; ci < 24; ++ci) {
      const float* cp = &s2[ci * 256];
#pragma unroll
      for (int ky = 0; ky < 3; ++ky) {
        int iy = 2 * oy + ky - 1;
        if (iy < 0 || iy >= 16) continue;
#pragma unroll
        for (int kx = 0; kx < 3; ++kx) {
          int ix = 2 * ox + kx - 1;
          if (ix < 0 || ix >= 16) continue;
          float v = cp[iy * 16 + ix];
          const float* wp = &sw[((ky * 3 + kx) * 24 + ci) * 24 + cog * 6];
#pragma unroll
          for (int u = 0; u < 6; ++u) acc[u] += v * wp[u];
        }
      }
    }
#pragma unroll
    for (int u = 0; u < 6; ++u) {
      int co = cog * 6 + u;
      s3[co * 64 + pos] = fmaxf(acc[u] * bs3[co] + bb3[co], 0.f);
    }
  }
  // embed: thread t = output feature column
  float wa[26], wb[26];
#pragma unroll
  for (int c = 0; c < 26; ++c) {
    wa[c] = gw1[c * 256 + t];
    wb[c] = gw1[(26 + c) * 256 + t];
  }
  __syncthreads();
  for (int p = 0; p < 64; ++p) {
    float a = 0.f, b = 0.f;
#pragma unroll
    for (int c = 0; c < 24; ++c) {
      float v = s3[c * 64 + p];
      a += v * wa[c];
      b += v * wb[c];
    }
    float cx = -1.f + (2.f / 7.f) * (float)(p & 7);
    float cy = -1.f + (2.f / 7.f) * (float)(p >> 3);
    a += cx * wa[24] + cy * wa[25];
    b += cx * wb[24] + cy * wb[25];
    hi[(size_t)(n * 64 + p) * 256 + t] = a;
    hj[(size_t)(n * 64 + p) * 256 + t] = b;
  }
}

// ---------------- K4: fused relation network (R3-proven 8x4 tiling) ----------------
// Waves tile columns DISJOINTLY (wave*64): each weight column read once per block.
__global__ __launch_bounds__(256, 2)
void g_fused(const float* __restrict__ hi, const float* __restrict__ hj,
             const float* __restrict__ hq, const __bf16* __restrict__ Wt,
             const float* __restrict__ b2, const float* __restrict__ b3,
             const float* __restrict__ b4, float* __restrict__ s_out) {
  const int blk = blockIdx.x;          // n*32 + ib ; i = 2*ib, 2*ib+1
  const int n = blk >> 5, ib = blk & 31;
  const int tid = threadIdx.x;
  const int wave = tid >> 6, lane = tid & 63;
  const int q = lane >> 4, lr = lane & 15;

  __shared__ __align__(16) __bf16 Hs[128 * LH];

  const int c0 = (tid & 63) * 4;
  float4 hq4 = *(const float4*)(hq + (size_t)n * 256 + c0);
  float4 h0 = *(const float4*)(hi + (size_t)(n * 64 + ib * 2)     * 256 + c0);
  float4 h1 = *(const float4*)(hi + (size_t)(n * 64 + ib * 2 + 1) * 256 + c0);
  h0.x += hq4.x; h0.y += hq4.y; h0.z += hq4.z; h0.w += hq4.w;
  h1.x += hq4.x; h1.y += hq4.y; h1.z += hq4.z; h1.w += hq4.w;

  const int colloc = wave * 64 + lr;   // + c*16 per col-tile
  // Hoist all bias scalar loads (12 values) before the compute to overlap latency.
  float bias[3][4];
#pragma unroll
  for (int c = 0; c < 4; ++c) {
    bias[0][c] = b2[colloc + c * 16];
    bias[1][c] = b3[colloc + c * 16];
    bias[2][c] = b4[colloc + c * 16];
  }

  const float* hjb = hj + (size_t)n * 64 * 256;
#pragma unroll
  for (int it = 0; it < 16; ++it) {
    int j = it * 4 + wave;
    float4 v = *(const float4*)(hjb + j * 256 + c0);
    bf16x4 o;
    o[0] = (__bf16)fmaxf(v.x + h0.x, 0.f);
    o[1] = (__bf16)fmaxf(v.y + h0.y, 0.f);
    o[2] = (__bf16)fmaxf(v.z + h0.z, 0.f);
    o[3] = (__bf16)fmaxf(v.w + h0.w, 0.f);
    *(bf16x4*)&Hs[j * LH + c0] = o;
    bf16x4 o2;
    o2[0] = (__bf16)fmaxf(v.x + h1.x, 0.f);
    o2[1] = (__bf16)fmaxf(v.y + h1.y, 0.f);
    o2[2] = (__bf16)fmaxf(v.z + h1.z, 0.f);
    o2[3] = (__bf16)fmaxf(v.w + h1.w, 0.f);
    *(bf16x4*)&Hs[(64 + j) * LH + c0] = o2;
  }
  __syncthreads();

  const __bf16* Bp = Wt + (size_t)wave * 2048 + lr * 32 + q * 8;

  for (int l = 0; l < 3; ++l) {
    const __bf16* Bl = Bp + (size_t)l * 65536;

    f32x4 acc[8][4];
#pragma unroll
    for (int r = 0; r < 8; ++r)
#pragma unroll
      for (int c = 0; c < 4; ++c) acc[r][c] = (f32x4){0.f, 0.f, 0.f, 0.f};

    for (int ks = 0; ks < 8; ++ks) {
      bf16x8 b[4];
#pragma unroll
      for (int c = 0; c < 4; ++c)
        b[c] = *(const bf16x8*)&Bl[ks * 8192 + c * 512];
      bf16x8 a[8];
#pragma unroll
      for (int r = 0; r < 8; ++r)
        a[r] = *(const bf16x8*)&Hs[(r * 16 + lr) * LH + ks * 32 + q * 8];
#pragma unroll
      for (int r = 0; r < 8; ++r)
#pragma unroll
        for (int c = 0; c < 4; ++c)
          acc[r][c] = __builtin_amdgcn_mfma_f32_16x16x32_bf16(a[r], b[c], acc[r][c], 0, 0, 0);
    }

    if (l < 2) {
      __syncthreads();
#pragma unroll
      for (int r = 0; r < 8; ++r)
#pragma unroll
        for (int c = 0; c < 4; ++c)
#pragma unroll
          for (int reg = 0; reg < 4; ++reg) {
            int row = r * 16 + q * 4 + reg;    // C/D: row = quad*4 + reg
            Hs[row * LH + colloc + c * 16] = (__bf16)fmaxf(acc[r][c][reg] + bias[l][c], 0.f);
          }
      __syncthreads();
    } else {
      // final layer: relu + column-sum over all 128 rows, then atomicAdd
#pragma unroll
      for (int c = 0; c < 4; ++c) {
        float cs = 0.f;
#pragma unroll
        for (int r = 0; r < 8; ++r)
#pragma unroll
          for (int reg = 0; reg < 4; ++reg)
            cs += fmaxf(acc[r][c][reg] + bias[2][c], 0.f);
        cs += __shfl_xor(cs, 16);
        cs += __shfl_xor(cs, 32);
        if (q == 0) atomicAdd(&s_out[n * 256 + colloc + c * 16], cs);
      }
    }
  }
}

// ---------------- K5: f-network + classifier + log_softmax ----------------
__global__ void f_net(const float* __restrict__ s, const float* __restrict__ fw1,
                      const float* __restrict__ fb1, const float* __restrict__ fw2,
                      const float* __restrict__ fb2, const float* __restrict__ cw,
                      const float* __restrict__ cb, float* __restrict__ out) {
  int n = blockIdx.x, t = threadIdx.x;
  __shared__ float buf[256], buf2[256], zs[32];
  buf[t] = s[n * 256 + t];
  __syncthreads();
  float a = fb1[t];
  for (int c = 0; c < 256; ++c) a += buf[c] * fw1[c * 256 + t];
  a = fmaxf(a, 0.f);
  buf2[t] = a;
  __syncthreads();
  float y = fb2[t];
  for (int c = 0; c < 256; ++c) y += buf2[c] * fw2[c * 256 + t];
  y = fmaxf(y, 0.f);
  __syncthreads();
  buf[t] = y;
  __syncthreads();
  float z = 0.f;
  if (t < 32) {
    z = cb[t];
    for (int c = 0; c < 256; ++c) z += buf[c] * cw[c * 32 + t];
    zs[t] = z;
  }
  __syncthreads();
  if (t < 32) {
    float m = -1e30f;
    for (int c = 0; c < 32; ++c) m = fmaxf(m, zs[c]);
    float se = 0.f;
    for (int c = 0; c < 32; ++c) se += expf(zs[c] - m);
    out[n * 32 + t] = z - m - logf(se);
  }
}

extern "C" void kernel_launch(void* const* d_in, const int* in_sizes, int n_in,
                              void* d_out, int out_size, void* d_ws, size_t ws_size,
                              hipStream_t stream) {
  const float* img  = (const float*)d_in[0];
  const float* qst  = (const float*)d_in[1];
  const float* w0   = (const float*)d_in[2];
  const float* w1   = (const float*)d_in[3];
  const float* w2   = (const float*)d_in[4];
  const float* w3   = (const float*)d_in[5];
  const float* bs0  = (const float*)d_in[6];
  const float* bb0  = (const float*)d_in[7];
  const float* bs1  = (const float*)d_in[8];
  const float* bb1  = (const float*)d_in[9];
  const float* bs2  = (const float*)d_in[10];
  const float* bb2  = (const float*)d_in[11];
  const float* bs3  = (const float*)d_in[12];
  const float* bb3  = (const float*)d_in[13];
  const float* gw1  = (const float*)d_in[14];
  const float* gb1  = (const float*)d_in[15];
  const float* gw2  = (const float*)d_in[16];
  const float* gb2  = (const float*)d_in[17];
  const float* gw3  = (const float*)d_in[18];
  const float* gb3  = (const float*)d_in[19];
  const float* gw4  = (const float*)d_in[20];
  const float* gb4  = (const float*)d_in[21];
  const float* fw1  = (const float*)d_in[22];
  const float* fb1  = (const float*)d_in[23];
  const float* fw2  = (const float*)d_in[24];
  const float* fb2  = (const float*)d_in[25];
  const float* cw   = (const float*)d_in[26];
  const float* cb   = (const float*)d_in[27];

  char* ws = (char*)d_ws;
  float* c0 = (float*)(ws + 0);                    // 25,165,824 B (dead after conv1 reads it)
  float* c1 = (float*)(ws + 25165824);             //  6,291,456 B -> 31,457,280
  __bf16* Wt  = (__bf16*)(ws + 31457280);          //   393,216 B -> 31,850,496 (outside c0)
  float*  hqb = (float*)(ws + 31850496);           //    65,536 B -> 31,916,032
  float*  sbuf = (float*)(ws + 31916032);          //    65,536 B -> 31,981,568
  float*  hi  = (float*)(ws + 0);                  // 4,194,304 B (dead-c0, written in K3)
  float*  hj  = (float*)(ws + 4194304);            // 4,194,304 B

  k1<<<600, 256, 0, stream>>>(img, w0, bs0, bb0, gw2, gw3, gw4, gw1, gb1, qst,
                              c0, Wt, hqb, sbuf);
  conv1_k<<<256, 256, 0, stream>>>(c0, w1, bs1, bb1, c1);
  chain2_k<<<64, 256, 0, stream>>>(c1, w2, bs2, bb2, w3, bs3, bb3, gw1, hi, hj);
  g_fused<<<2048, 256, 0, stream>>>(hi, hj, hqb, Wt, gb2, gb3, gb4, sbuf);
  f_net<<<64, 256, 0, stream>>>(sbuf, fw1, fb1, fw2, fb2, cw, cb, (float*)d_out);
}